// Round 1
// baseline (590.142 us; speedup 1.0000x reference)
//
#include <hip/hip_runtime.h>

#define NB   32
#define HW   4096
#define DD   256
#define NPQ  512
#define NQ   3
#define NPOS 10
#define NROWS (NB * NQ * NPOS)   // 960

__device__ __forceinline__ float dot4(float4 a, float4 b) {
    return a.x * b.x + a.y * b.y + a.z * b.z + a.w * b.w;
}

// ---------------------------------------------------------------------------
// Kernel A: attn[b,q,row] = dot(z[b, rand_idx[b,q], :], z_pos[b, row, :])
// One wave per row per iteration: lane i holds float4 chunk (16B coalesced,
// 1KB/row). Grid (32 batches, 32 chunks of 128 rows) = 1024 blocks -> 4
// blocks/CU, 16 waves/CU; 2-row unroll for in-flight HBM bytes.
// ---------------------------------------------------------------------------
__global__ __launch_bounds__(256) void attn_kernel(
    const float* __restrict__ z, const float* __restrict__ z_pos,
    const int* __restrict__ rand_idx, float* __restrict__ attn)
{
    const int b    = blockIdx.x;
    const int row0 = blockIdx.y * 128;
    const int wave = threadIdx.x >> 6;
    const int lane = threadIdx.x & 63;

    const size_t zb = (size_t)b * HW;
    const float4 s0 = *(const float4*)(z + (zb + rand_idx[b * NQ + 0]) * DD + lane * 4);
    const float4 s1 = *(const float4*)(z + (zb + rand_idx[b * NQ + 1]) * DD + lane * 4);
    const float4 s2 = *(const float4*)(z + (zb + rand_idx[b * NQ + 2]) * DD + lane * 4);

    const float* zp  = z_pos + zb * DD;
    float* a0p = attn + ((size_t)b * NQ + 0) * HW;
    float* a1p = attn + ((size_t)b * NQ + 1) * HW;
    float* a2p = attn + ((size_t)b * NQ + 2) * HW;

    for (int i = 0; i < 32; i += 2) {
        const int rA = row0 + i * 4 + wave;
        const int rB = rA + 4;
        const float4 vA = *(const float4*)(zp + (size_t)rA * DD + lane * 4);
        const float4 vB = *(const float4*)(zp + (size_t)rB * DD + lane * 4);
        float a0 = dot4(vA, s0), a1 = dot4(vA, s1), a2 = dot4(vA, s2);
        float b0 = dot4(vB, s0), b1 = dot4(vB, s1), b2 = dot4(vB, s2);
        #pragma unroll
        for (int off = 32; off; off >>= 1) {
            a0 += __shfl_down(a0, off);
            a1 += __shfl_down(a1, off);
            a2 += __shfl_down(a2, off);
            b0 += __shfl_down(b0, off);
            b1 += __shfl_down(b1, off);
            b2 += __shfl_down(b2, off);
        }
        if (lane == 0) {
            a0p[rA] = a0; a1p[rA] = a1; a2p[rA] = a2;
            a0p[rB] = b0; a1p[rB] = b1; a2p[rB] = b2;
        }
    }
}

// ---------------------------------------------------------------------------
// Kernel B: top-10 indices per (b,q). One wave per (b,q): each lane keeps a
// sorted local top-10 of its 64 strided values, then 10 wave-argmax rounds
// (value desc, index asc tiebreak to match jax.lax.top_k — set is what
// matters downstream anyway).
// ---------------------------------------------------------------------------
__global__ __launch_bounds__(64) void topk_kernel(
    const float* __restrict__ attn, int* __restrict__ topk)
{
    const int bq   = blockIdx.x;      // 0..95
    const int lane = threadIdx.x;     // 0..63
    const float* row = attn + (size_t)bq * HW;

    float vals[NPOS];
    int   idxs[NPOS];
    #pragma unroll
    for (int i = 0; i < NPOS; i++) { vals[i] = -1e30f; idxs[i] = 0x7fffffff; }

    for (int j = 0; j < HW / 64; j++) {
        const int   c = lane + j * 64;
        const float v = row[c];
        if (v > vals[NPOS - 1]) {
            int pos = NPOS - 1;
            while (pos > 0 && v > vals[pos - 1]) {
                vals[pos] = vals[pos - 1];
                idxs[pos] = idxs[pos - 1];
                pos--;
            }
            vals[pos] = v;
            idxs[pos] = c;
        }
    }

    int ptr = 0;
    for (int k = 0; k < NPOS; k++) {
        const float v  = (ptr < NPOS) ? vals[ptr] : -1e30f;
        const int   id = (ptr < NPOS) ? idxs[ptr] : 0x7fffffff;
        float bv = v;
        int   bi = id;
        #pragma unroll
        for (int off = 32; off; off >>= 1) {
            const float ov = __shfl_xor(bv, off);
            const int   oi = __shfl_xor(bi, off);
            if (ov > bv || (ov == bv && oi < bi)) { bv = ov; bi = oi; }
        }
        if (id == bi) ptr++;          // column indices are unique -> exactly one winner
        if (lane == 0) topk[bq * NPOS + k] = bi;
    }
}

// ---------------------------------------------------------------------------
// Kernel C: per-row JSD partial sums. Row r pairs
//   p = z_dis[bi, rand_idx[bi, r%3]]          (the reference's broadcast quirk)
//   t = z_pos_dis[bi, topk[bi, (r%30)/10, r%10]]
// contribution = xlogy(p,p) + xlogy(t,t) - (p+t)*log(clip((p+t)/2,1e-7,1))
// ---------------------------------------------------------------------------
__global__ __launch_bounds__(256) void jsd_kernel(
    const float* __restrict__ z_dis, const float* __restrict__ z_pos_dis,
    const int* __restrict__ rand_idx, const int* __restrict__ topk,
    float* __restrict__ partial)
{
    const int r    = blockIdx.x;      // 0..959
    const int bi   = r / 30;
    const int rem  = r % 30;
    const int q    = rem % 3;
    const int q2   = rem / 10;
    const int pos2 = rem % 10;

    const int pidx = rand_idx[bi * NQ + q];
    const int tidx = topk[(bi * NQ + q2) * NPOS + pos2];
    const float* prow = z_dis     + ((size_t)bi * HW + pidx) * NPQ;
    const float* trow = z_pos_dis + ((size_t)bi * HW + tidx) * NPQ;

    float acc = 0.f;
    #pragma unroll
    for (int j = 0; j < NPQ / 256; j++) {
        const int c = threadIdx.x + j * 256;
        const float p = prow[c];
        const float t = trow[c];
        float m = 0.5f * (p + t);
        m = fminf(fmaxf(m, 1e-7f), 1.0f);
        const float lm = __logf(m);
        const float xp = (p > 0.f) ? p * __logf(p) : 0.f;
        const float xt = (t > 0.f) ? t * __logf(t) : 0.f;
        acc += xp + xt - (p + t) * lm;
    }

    #pragma unroll
    for (int off = 32; off; off >>= 1) acc += __shfl_down(acc, off);
    __shared__ float s[4];
    if ((threadIdx.x & 63) == 0) s[threadIdx.x >> 6] = acc;
    __syncthreads();
    if (threadIdx.x == 0) partial[r] = s[0] + s[1] + s[2] + s[3];
}

// ---------------------------------------------------------------------------
// Kernel D: reduce 960 partials -> out[0] = sum * 0.5 / 960
// ---------------------------------------------------------------------------
__global__ __launch_bounds__(1024) void final_kernel(
    const float* __restrict__ partial, float* __restrict__ out)
{
    float acc = (threadIdx.x < NROWS) ? partial[threadIdx.x] : 0.f;
    #pragma unroll
    for (int off = 32; off; off >>= 1) acc += __shfl_down(acc, off);
    __shared__ float s[16];
    if ((threadIdx.x & 63) == 0) s[threadIdx.x >> 6] = acc;
    __syncthreads();
    if (threadIdx.x == 0) {
        float t = 0.f;
        #pragma unroll
        for (int i = 0; i < 16; i++) t += s[i];
        out[0] = t * (0.5f / NROWS);
    }
}

extern "C" void kernel_launch(void* const* d_in, const int* in_sizes, int n_in,
                              void* d_out, int out_size, void* d_ws, size_t ws_size,
                              hipStream_t stream)
{
    const float* z         = (const float*)d_in[0];
    const float* z_pos     = (const float*)d_in[1];
    const float* z_dis     = (const float*)d_in[2];
    const float* z_pos_dis = (const float*)d_in[3];
    const int*   rand_idx  = (const int*)d_in[4];
    float* out = (float*)d_out;

    char* ws = (char*)d_ws;
    float* attn    = (float*)ws;                                 // 32*3*4096 floats = 1.5 MB
    int*   topk    = (int*)(ws + (size_t)NB * NQ * HW * 4);      // 960 ints
    float* partial = (float*)(ws + (size_t)NB * NQ * HW * 4 + 4096); // 960 floats

    attn_kernel <<<dim3(NB, 32), 256, 0, stream>>>(z, z_pos, rand_idx, attn);
    topk_kernel <<<NB * NQ, 64, 0, stream>>>(attn, topk);
    jsd_kernel  <<<NROWS, 256, 0, stream>>>(z_dis, z_pos_dis, rand_idx, topk, partial);
    final_kernel<<<1, 1024, 0, stream>>>(partial, out);
}

// Round 2
// 552.961 us; speedup vs baseline: 1.0672x; 1.0672x over previous
//
#include <hip/hip_runtime.h>

#define NB   32
#define HW   4096
#define DD   256
#define NPQ  512
#define NQ   3
#define NPOS 10
#define NCHUNK 32               // 128 rows per chunk
#define NROWS (NB * NQ * NPOS)  // 960

__device__ __forceinline__ float dot4(float4 a, float4 b) {
    return a.x * b.x + a.y * b.y + a.z * b.z + a.w * b.w;
}

// ---------------------------------------------------------------------------
// Kernel A: attn scores for a 128-row chunk -> LDS -> per-chunk top-10
// candidates per query. One wave per row per iteration (1KB coalesced float4
// row load, shuffle-reduce 3 dots). Grid (32 b, 32 chunks) = 1024 blocks ->
// 4 blocks/CU, 16 waves/CU. No global attn buffer: scores stay in LDS and
// each block emits 10 (val,idx) candidates per query.
// ---------------------------------------------------------------------------
__global__ __launch_bounds__(256) void attn_topk_kernel(
    const float* __restrict__ z, const float* __restrict__ z_pos,
    const int* __restrict__ rand_idx,
    float* __restrict__ cand_val, int* __restrict__ cand_idx)
{
    const int b     = blockIdx.x;
    const int chunk = blockIdx.y;
    const int row0  = chunk * 128;
    const int wave  = threadIdx.x >> 6;
    const int lane  = threadIdx.x & 63;

    __shared__ float sv[NQ][128];

    const size_t zb = (size_t)b * HW;
    const float4 s0 = *(const float4*)(z + (zb + rand_idx[b * NQ + 0]) * DD + lane * 4);
    const float4 s1 = *(const float4*)(z + (zb + rand_idx[b * NQ + 1]) * DD + lane * 4);
    const float4 s2 = *(const float4*)(z + (zb + rand_idx[b * NQ + 2]) * DD + lane * 4);

    const float* zp = z_pos + zb * DD;

    for (int i = 0; i < 32; i += 2) {
        const int lrA = i * 4 + wave;        // local row 0..127
        const int lrB = lrA + 4;
        const float4 vA = *(const float4*)(zp + (size_t)(row0 + lrA) * DD + lane * 4);
        const float4 vB = *(const float4*)(zp + (size_t)(row0 + lrB) * DD + lane * 4);
        float a0 = dot4(vA, s0), a1 = dot4(vA, s1), a2 = dot4(vA, s2);
        float b0 = dot4(vB, s0), b1 = dot4(vB, s1), b2 = dot4(vB, s2);
        #pragma unroll
        for (int off = 32; off; off >>= 1) {
            a0 += __shfl_down(a0, off);
            a1 += __shfl_down(a1, off);
            a2 += __shfl_down(a2, off);
            b0 += __shfl_down(b0, off);
            b1 += __shfl_down(b1, off);
            b2 += __shfl_down(b2, off);
        }
        if (lane == 0) {
            sv[0][lrA] = a0; sv[1][lrA] = a1; sv[2][lrA] = a2;
            sv[0][lrB] = b0; sv[1][lrB] = b1; sv[2][lrB] = b2;
        }
    }
    __syncthreads();

    // Waves 0..2: top-10 of this chunk's 128 scores for query `wave`.
    if (wave < NQ) {
        float v0 = sv[wave][lane];
        float v1 = sv[wave][lane + 64];
        int   i0 = row0 + lane;
        int   i1 = row0 + lane + 64;
        if (v1 > v0 || (v1 == v0 && i1 < i0)) {
            float tv = v0; v0 = v1; v1 = tv;
            int   ti = i0; i0 = i1; i1 = ti;
        }
        float lv[2] = {v0, v1};
        int   li[2] = {i0, i1};
        int ptr = 0;

        float* cv = cand_val + ((size_t)(b * NQ + wave) * NCHUNK + chunk) * NPOS;
        int*   ci = cand_idx + ((size_t)(b * NQ + wave) * NCHUNK + chunk) * NPOS;

        for (int k = 0; k < NPOS; k++) {
            const float v  = (ptr < 2) ? lv[ptr] : -1e30f;
            const int   id = (ptr < 2) ? li[ptr] : 0x7fffffff;
            float bv = v;
            int   bi = id;
            #pragma unroll
            for (int off = 32; off; off >>= 1) {
                const float ov = __shfl_xor(bv, off);
                const int   oi = __shfl_xor(bi, off);
                if (ov > bv || (ov == bv && oi < bi)) { bv = ov; bi = oi; }
            }
            if (id == bi && ptr < 2) ptr++;   // row indices unique -> one winner
            if (lane == 0) { cv[k] = bv; ci[k] = bi; }
        }
    }
}

// ---------------------------------------------------------------------------
// Kernel B: merge 32 chunks x 10 candidates -> final top-10 per (b,q).
// One wave per (b,q); lane holds 5 candidates sorted desc, 10 argmax rounds.
// Also zeroes d_out for kernel C's atomics (stream order guarantees this
// happens before any jsd atomicAdd).
// ---------------------------------------------------------------------------
__global__ __launch_bounds__(64) void merge_kernel(
    const float* __restrict__ cand_val, const int* __restrict__ cand_idx,
    int* __restrict__ topk, float* __restrict__ out)
{
    const int bq   = blockIdx.x;     // 0..95
    const int lane = threadIdx.x;

    if (bq == 0 && lane == 0) out[0] = 0.f;

    float lv[5];
    int   li[5];
    #pragma unroll
    for (int i = 0; i < 5; i++) { lv[i] = -1e30f; li[i] = 0x7fffffff; }

    #pragma unroll
    for (int j = 0; j < 5; j++) {
        const int   src = bq * (NCHUNK * NPOS) + j * 64 + lane;
        const float v   = cand_val[src];
        const int   id  = cand_idx[src];
        int pos = 4;
        if (v > lv[4] || (v == lv[4] && id < li[4])) {
            while (pos > 0 && (v > lv[pos - 1] || (v == lv[pos - 1] && id < li[pos - 1]))) {
                lv[pos] = lv[pos - 1];
                li[pos] = li[pos - 1];
                pos--;
            }
            lv[pos] = v;
            li[pos] = id;
        }
    }

    int ptr = 0;
    for (int k = 0; k < NPOS; k++) {
        const float v  = (ptr < 5) ? lv[ptr] : -1e30f;
        const int   id = (ptr < 5) ? li[ptr] : 0x7fffffff;
        float bv = v;
        int   bi = id;
        #pragma unroll
        for (int off = 32; off; off >>= 1) {
            const float ov = __shfl_xor(bv, off);
            const int   oi = __shfl_xor(bi, off);
            if (ov > bv || (ov == bv && oi < bi)) { bv = ov; bi = oi; }
        }
        if (id == bi && ptr < 5) ptr++;
        if (lane == 0) topk[bq * NPOS + k] = bi;
    }
}

// ---------------------------------------------------------------------------
// Kernel C: JSD partial sums, 96 blocks x 10 rows each, atomicAdd to out.
// Row r (global 0..959): bi=r/30, rem=r%30; p-row = z_dis[bi, rand_idx[bi, rem%3]]
// (reference broadcast quirk), t-row = z_pos_dis[bi, topk[bi, rem/10, rem%10]].
// Block bq covers rows with bi=bq/3, qB=bq%3 (rem in [qB*10, qB*10+10)).
// ---------------------------------------------------------------------------
__global__ __launch_bounds__(256) void jsd_kernel(
    const float* __restrict__ z_dis, const float* __restrict__ z_pos_dis,
    const int* __restrict__ rand_idx, const int* __restrict__ topk,
    float* __restrict__ out)
{
    const int bq = blockIdx.x;       // 0..95
    const int bi = bq / NQ;
    const int qB = bq % NQ;

    float acc = 0.f;
    for (int pos = 0; pos < NPOS; pos++) {
        const int rem  = qB * NPOS + pos;
        const int qA   = rem % NQ;
        const int pidx = rand_idx[bi * NQ + qA];
        const int tidx = topk[bq * NPOS + pos];
        const float* prow = z_dis     + ((size_t)bi * HW + pidx) * NPQ;
        const float* trow = z_pos_dis + ((size_t)bi * HW + tidx) * NPQ;
        #pragma unroll
        for (int j = 0; j < NPQ / 256; j++) {
            const int c = threadIdx.x + j * 256;
            const float p = prow[c];
            const float t = trow[c];
            float m = 0.5f * (p + t);
            m = fminf(fmaxf(m, 1e-7f), 1.0f);
            const float lm = __logf(m);
            const float xp = (p > 0.f) ? p * __logf(p) : 0.f;
            const float xt = (t > 0.f) ? t * __logf(t) : 0.f;
            acc += xp + xt - (p + t) * lm;
        }
    }

    #pragma unroll
    for (int off = 32; off; off >>= 1) acc += __shfl_down(acc, off);
    __shared__ float s[4];
    if ((threadIdx.x & 63) == 0) s[threadIdx.x >> 6] = acc;
    __syncthreads();
    if (threadIdx.x == 0)
        atomicAdd(out, (s[0] + s[1] + s[2] + s[3]) * (0.5f / NROWS));
}

extern "C" void kernel_launch(void* const* d_in, const int* in_sizes, int n_in,
                              void* d_out, int out_size, void* d_ws, size_t ws_size,
                              hipStream_t stream)
{
    const float* z         = (const float*)d_in[0];
    const float* z_pos     = (const float*)d_in[1];
    const float* z_dis     = (const float*)d_in[2];
    const float* z_pos_dis = (const float*)d_in[3];
    const int*   rand_idx  = (const int*)d_in[4];
    float* out = (float*)d_out;

    char* ws = (char*)d_ws;
    const size_t n_cand = (size_t)NB * NQ * NCHUNK * NPOS;     // 30720
    float* cand_val = (float*)ws;                               // 122880 B
    int*   cand_idx = (int*)(ws + n_cand * 4);                  // 122880 B
    int*   topk     = (int*)(ws + n_cand * 8);                  // 3840 B

    attn_topk_kernel<<<dim3(NB, NCHUNK), 256, 0, stream>>>(z, z_pos, rand_idx,
                                                           cand_val, cand_idx);
    merge_kernel<<<NB * NQ, 64, 0, stream>>>(cand_val, cand_idx, topk, out);
    jsd_kernel<<<NB * NQ, 256, 0, stream>>>(z_dis, z_pos_dis, rand_idx, topk, out);
}